// Round 5
// baseline (454.734 us; speedup 1.0000x reference)
//
#include <hip/hip_runtime.h>
#include <math.h>
#include <stdint.h>

#define B_ 8
#define H_ 512
#define E_ 256
#define T_ 2048
#define S_ 2048
static constexpr float SCALE = 0.83666002653407555f; // sqrt(0.7)
static constexpr float ESHIFT = 60.0f; // constant softmax shift: exact identity, f32-safe

typedef _Float16 half8 __attribute__((ext_vector_type(8)));
typedef _Float16 half4v __attribute__((ext_vector_type(4)));
typedef short short8 __attribute__((ext_vector_type(8)));
typedef unsigned short ushort8v __attribute__((ext_vector_type(8)));
typedef unsigned short ushort4v __attribute__((ext_vector_type(4)));
typedef float f32x4 __attribute__((ext_vector_type(4)));

__device__ __forceinline__ unsigned short f2bf(float f) { // RNE f32->bf16
    unsigned int u = __float_as_uint(f);
    u += 0x7FFFu + ((u >> 16) & 1u);
    return (unsigned short)(u >> 16);
}
__device__ __forceinline__ float bf2f(unsigned short u) {
    return __uint_as_float(((unsigned int)u) << 16);
}

// ---- fused fp32->fp16 casts for enc, W_h2e, W_e2h (one launch) ----
__global__ __launch_bounds__(256) void k_cast_all(const float* __restrict__ enc,
                                                  const float* __restrict__ w1,
                                                  const float* __restrict__ w2,
                                                  _Float16* __restrict__ encK,
                                                  _Float16* __restrict__ W1b,
                                                  _Float16* __restrict__ W2b) {
    const int i = blockIdx.x * 256 + threadIdx.x;
    const int N1 = B_ * S_ * E_ / 8;      // 524288
    const int N2 = E_ * H_ / 8;           // 16384
    const float* src; _Float16* dst; int off;
    if (i < N1)            { src = enc; dst = encK; off = i; }
    else if (i < N1 + N2)  { src = w1;  dst = W1b;  off = i - N1; }
    else                   { src = w2;  dst = W2b;  off = i - N1 - N2; }
    const float4* p = (const float4*)(src + (size_t)off * 8);
    const float4 a = p[0], b = p[1];
    half8 v;
    v[0] = (_Float16)a.x; v[1] = (_Float16)a.y; v[2] = (_Float16)a.z; v[3] = (_Float16)a.w;
    v[4] = (_Float16)b.x; v[5] = (_Float16)b.y; v[6] = (_Float16)b.z; v[7] = (_Float16)b.w;
    *(half8*)(dst + (size_t)off * 8) = v;
}

// ---- transpose + cast f16: in fp32 [Z,R,C] -> out fp16 [Z,C,R] ----
__global__ __launch_bounds__(256) void k_tcast(const float* __restrict__ in,
                                               _Float16* __restrict__ out, int R, int C) {
    __shared__ float tile[32][33];
    const size_t nb = (size_t)R * C;
    const float* inb = in + (size_t)blockIdx.z * nb;
    _Float16* outb = out + (size_t)blockIdx.z * nb;
    const int c0 = blockIdx.x * 32, r0 = blockIdx.y * 32;
    const int tr = threadIdx.x >> 3;
    const int tc = (threadIdx.x & 7) * 4;
    const float4 v = *(const float4*)(inb + (size_t)(r0 + tr) * C + c0 + tc);
    tile[tr][tc + 0] = v.x; tile[tr][tc + 1] = v.y;
    tile[tr][tc + 2] = v.z; tile[tr][tc + 3] = v.w;
    __syncthreads();
    half4v o;
    o[0] = (_Float16)tile[tc + 0][tr]; o[1] = (_Float16)tile[tc + 1][tr];
    o[2] = (_Float16)tile[tc + 2][tr]; o[3] = (_Float16)tile[tc + 3][tr];
    *(half4v*)(outb + (size_t)(c0 + tr) * R + r0 + tc) = o;
}

// ---- transpose + cast bf16: in fp32 [Z,R,C] -> out bf16 [Z,C,R] ----
__global__ __launch_bounds__(256) void k_tcast_bf(const float* __restrict__ in,
                                                  unsigned short* __restrict__ out, int R, int C) {
    __shared__ float tile[32][33];
    const size_t nb = (size_t)R * C;
    const float* inb = in + (size_t)blockIdx.z * nb;
    unsigned short* outb = out + (size_t)blockIdx.z * nb;
    const int c0 = blockIdx.x * 32, r0 = blockIdx.y * 32;
    const int tr = threadIdx.x >> 3;
    const int tc = (threadIdx.x & 7) * 4;
    const float4 v = *(const float4*)(inb + (size_t)(r0 + tr) * C + c0 + tc);
    tile[tr][tc + 0] = v.x; tile[tr][tc + 1] = v.y;
    tile[tr][tc + 2] = v.z; tile[tr][tc + 3] = v.w;
    __syncthreads();
    ushort4v o;
    o[0] = f2bf(tile[tc + 0][tr]); o[1] = f2bf(tile[tc + 1][tr]);
    o[2] = f2bf(tile[tc + 2][tr]); o[3] = f2bf(tile[tc + 3][tr]);
    *(ushort4v*)(outb + (size_t)(c0 + tr) * R + r0 + tc) = o;
}

// ---- async 16B global->LDS ----
__device__ __forceinline__ void gl_lds16(const _Float16* g, _Float16* l) {
    __builtin_amdgcn_global_load_lds(
        (const __attribute__((address_space(1))) void*)g,
        (__attribute__((address_space(3))) void*)l, 16, 0, 0);
}

// stage 128x32 2B-elem tile (rows k-contiguous) -> linear [128][32] LDS
__device__ __forceinline__ void stage128x32_gl(const _Float16* __restrict__ g, int ld,
                                               _Float16* __restrict__ lds, int wv, int l) {
    const int r = (wv << 4) + (l >> 2);
    const int c = (l & 3) << 3;
    gl_lds16(g + (size_t)r * ld + c, lds + (wv << 9));
    gl_lds16(g + (size_t)(r + 64) * ld + c, lds + ((wv + 4) << 9));
}

// stage 64x32 tile
__device__ __forceinline__ void stage64x32_gl(const _Float16* __restrict__ g, int ld,
                                              _Float16* __restrict__ lds, int wv, int l) {
    const int r = (wv << 4) + (l >> 2);
    const int c = (l & 3) << 3;
    gl_lds16(g + (size_t)r * ld + c, lds + (wv << 9));
}

// ---- 128x128 tile (4 waves 2x2, acc 4x4) ----
#define MFMA_PROLOG                                                     \
    __shared__ __align__(16) _Float16 Ash[128 * 32];                    \
    __shared__ __align__(16) _Float16 Bsh[128 * 32];                    \
    const int tid = threadIdx.x;                                        \
    const int lane = tid & 63, wv = tid >> 6;                           \
    const int wm = (wv >> 1) * 64, wn = (wv & 1) * 64;                  \
    const int fr = lane & 15, fk = (lane >> 4) * 8;                     \
    f32x4 acc[4][4] = {};

#define MFMA_BODY                                                       \
    half8 af[4], bfr[4];                                                \
    _Pragma("unroll")                                                   \
    for (int i = 0; i < 4; ++i) {                                       \
        af[i]  = *(const half8*)&Ash[(wm + i * 16 + fr) * 32 + fk];     \
        bfr[i] = *(const half8*)&Bsh[(wn + i * 16 + fr) * 32 + fk];     \
    }                                                                   \
    _Pragma("unroll")                                                   \
    for (int mi = 0; mi < 4; ++mi)                                      \
        _Pragma("unroll")                                               \
        for (int ni = 0; ni < 4; ++ni)                                  \
            acc[mi][ni] = __builtin_amdgcn_mfma_f32_16x16x32_f16(       \
                af[mi], bfr[ni], acc[mi][ni], 0, 0, 0);

// ---- 64x128 tile (4 waves 2x2, acc 2x4) ----
#define MFMA_PROLOG64                                                   \
    __shared__ __align__(16) _Float16 Ash[64 * 32];                     \
    __shared__ __align__(16) _Float16 Bsh[128 * 32];                    \
    const int tid = threadIdx.x;                                        \
    const int lane = tid & 63, wv = tid >> 6;                           \
    const int wm = (wv >> 1) * 32, wn = (wv & 1) * 64;                  \
    const int fr = lane & 15, fk = (lane >> 4) * 8;                     \
    f32x4 acc[2][4] = {};

#define MFMA_BODY64                                                     \
    half8 af[2], bfr[4];                                                \
    _Pragma("unroll")                                                   \
    for (int i = 0; i < 2; ++i)                                         \
        af[i]  = *(const half8*)&Ash[(wm + i * 16 + fr) * 32 + fk];     \
    _Pragma("unroll")                                                   \
    for (int i = 0; i < 4; ++i)                                         \
        bfr[i] = *(const half8*)&Bsh[(wn + i * 16 + fr) * 32 + fk];     \
    _Pragma("unroll")                                                   \
    for (int mi = 0; mi < 2; ++mi)                                      \
        _Pragma("unroll")                                               \
        for (int ni = 0; ni < 4; ++ni)                                  \
            acc[mi][ni] = __builtin_amdgcn_mfma_f32_16x16x32_f16(       \
                af[mi], bfr[ni], acc[mi][ni], 0, 0, 0);

// K1: Q_f16[b,t,e] = f16((decT.W1^T + b_h2e + emb) * SCALE)
__global__ __launch_bounds__(256) void k_q_mfma(const _Float16* __restrict__ decT,
                                                const _Float16* __restrict__ W1,
                                                const float* __restrict__ bias,
                                                const float* __restrict__ emb,
                                                _Float16* __restrict__ Qb) {
    MFMA_PROLOG64
    const int b = blockIdx.z;
    const int t0 = blockIdx.y * 64;
    const int e0 = blockIdx.x * 128;
    const _Float16* Ab = decT + (size_t)b * T_ * H_ + (size_t)t0 * H_;
    const _Float16* Bb = W1 + (size_t)e0 * H_;
    for (int k0 = 0; k0 < H_; k0 += 32) {
        stage64x32_gl(Ab + k0, H_, Ash, wv, lane);
        stage128x32_gl(Bb + k0, H_, Bsh, wv, lane);
        __syncthreads();
        MFMA_BODY64
        __syncthreads();
    }
    const int cr = (lane >> 4) * 4, cn = lane & 15;
    const float* embb = emb + (size_t)b * T_ * E_;
    _Float16* Qo = Qb + (size_t)b * T_ * E_;
#pragma unroll
    for (int mi = 0; mi < 2; ++mi)
#pragma unroll
        for (int r = 0; r < 4; ++r) {
            const int t = t0 + wm + mi * 16 + cr + r;
#pragma unroll
            for (int ni = 0; ni < 4; ++ni) {
                const int e = e0 + wn + ni * 16 + cn;
                const float v = (acc[mi][ni][r] + bias[e] + embb[(size_t)t * E_ + e]) * SCALE;
                Qo[(size_t)t * E_ + e] = (_Float16)v;
            }
        }
}

// MEGA: energy + exp (P in LDS, bf16, swizzled) + row-sum + a-write + PV + ctx.
// One block = 32 t-rows of one batch. LDS: P 128KB + KV 16KB + reduce = 144.4KB.
__global__ __launch_bounds__(256) void k_mega(const _Float16* __restrict__ Qb,
                                              const _Float16* __restrict__ Kb,
                                              const _Float16* __restrict__ Vt,
                                              float* __restrict__ a_out,
                                              _Float16* __restrict__ ctxb) {
    __shared__ __align__(16) unsigned short Psh[32 * 2048];   // 131072 B, XOR-swizzled
    __shared__ __align__(16) _Float16 KVsh[256 * 32];         // 16384 B (K:[32s][256k], V:[256e][32k])
    __shared__ float partial[4][16];
    __shared__ float rowinv_sh[32];
    const int tid = threadIdx.x, lane = tid & 63, wv = tid >> 6;
    const int fr = lane & 15, fg = lane >> 4;
    const int t0 = blockIdx.x * 32, b = blockIdx.y;
    const _Float16* Qg = Qb + ((size_t)b * T_ + t0) * E_;
    const _Float16* Kg = Kb + (size_t)b * S_ * E_;
    const _Float16* Vg = Vt + (size_t)b * E_ * S_;

    // ---------- phase A: energy -> exp -> Psh, row-sum accumulate ----------
    const int wmA = (wv >> 1) * 16;  // t-half
    const int wsA = (wv & 1) * 16;   // s-half within 32-col chunk
    half8 qf[8];
#pragma unroll
    for (int kb = 0; kb < 8; ++kb)
        qf[kb] = *(const half8*)(Qg + (size_t)(wmA + fr) * E_ + kb * 32 + fg * 8);

    float rs[4] = {0.f, 0.f, 0.f, 0.f};
    for (int c = 0; c < 64; ++c) {
        // stage K chunk [c*32..+32) x 256, source-swizzled so swizzled ds_reads are conflict-free
        const _Float16* src = Kg + (size_t)(c * 32) * E_;
#pragma unroll
        for (int i = 0; i < 4; ++i) {
            const int L = i * 256 + tid;
            const int row = L >> 5, up = L & 31;
            gl_lds16(src + (size_t)row * E_ + ((up ^ (row & 7)) << 3),
                     KVsh + (size_t)(i * 256 + wv * 64) * 8);
        }
        __syncthreads();
        f32x4 acc = {};
#pragma unroll
        for (int kb = 0; kb < 8; ++kb) {
            const int row = wsA + fr;
            const int uir = (kb * 4 + fg) ^ (row & 7);
            const half8 bf = *(const half8*)&KVsh[row * 256 + uir * 8];
            acc = __builtin_amdgcn_mfma_f32_16x16x32_f16(qf[kb], bf, acc, 0, 0, 0);
        }
#pragma unroll
        for (int r = 0; r < 4; ++r) {
            const float p = __expf(acc[r] - ESHIFT);
            rs[r] += p;
            const int t = wmA + fg * 4 + r;
            const int s = c * 32 + wsA + fr;
            Psh[t * 2048 + (((s >> 3) ^ (t & 7)) << 3) + (s & 7)] = f2bf(p);
        }
        __syncthreads();
    }

    // ---------- row-sum reduce -> rowinv_sh ----------
#pragma unroll
    for (int m = 1; m < 16; m <<= 1)
#pragma unroll
        for (int r = 0; r < 4; ++r) rs[r] += __shfl_xor(rs[r], m);
    if (fr == 0)
#pragma unroll
        for (int r = 0; r < 4; ++r) partial[wv][fg * 4 + r] = rs[r];
    __syncthreads();
    if (tid < 32) {
        const int th = tid >> 4, lr = tid & 15;
        rowinv_sh[tid] = 1.0f / (partial[th * 2][lr] + partial[th * 2 + 1][lr]);
    }
    __syncthreads();

    // ---------- a-write: a[t,:] = bf2f(P) * inv (coalesced) ----------
    {
        float* ab = a_out + ((size_t)b * T_ + t0) * S_;
        for (int r = 0; r < 32; ++r) {
            const float inv = rowinv_sh[r];
            const ushort8v v = *(const ushort8v*)&Psh[r * 2048 + ((tid ^ (r & 7)) << 3)];
            float4 o0, o1;
            o0.x = bf2f(v[0]) * inv; o0.y = bf2f(v[1]) * inv;
            o0.z = bf2f(v[2]) * inv; o0.w = bf2f(v[3]) * inv;
            o1.x = bf2f(v[4]) * inv; o1.y = bf2f(v[5]) * inv;
            o1.z = bf2f(v[6]) * inv; o1.w = bf2f(v[7]) * inv;
            float* dst = ab + (size_t)r * S_ + tid * 8;
            ((float4*)dst)[0] = o0;
            ((float4*)dst)[1] = o1;
        }
    }

    // ---------- phase B: ctx = (P . V) * inv ----------
    const int wmB = (wv >> 1) * 16;   // t-half
    const int weB = (wv & 1) * 128;   // e-half
    f32x4 acc2[8] = {};
    for (int ks = 0; ks < 64; ++ks) {
        // stage V tile [256 e][32 s], source-swizzled (unit' = unit ^ ((e>>1)&3))
#pragma unroll
        for (int i = 0; i < 4; ++i) {
            const int L = i * 256 + tid;
            const int e = L >> 2, up = L & 3;
            gl_lds16(Vg + (size_t)e * S_ + ks * 32 + ((up ^ ((e >> 1) & 3)) << 3),
                     KVsh + (size_t)(i * 256 + wv * 64) * 8);
        }
        __syncthreads();
        const int t = wmB + fr;
        const int pu = (ks * 4 + fg) ^ (t & 7);
        const short8 af = *(const short8*)&Psh[t * 2048 + pu * 8];
#pragma unroll
        for (int nt = 0; nt < 8; ++nt) {
            const int e = weB + nt * 16 + fr;
            const int vu = fg ^ ((e >> 1) & 3);
            const short8 bf = *(const short8*)&KVsh[e * 32 + vu * 8];
            acc2[nt] = __builtin_amdgcn_mfma_f32_16x16x32_bf16(af, bf, acc2[nt], 0, 0, 0);
        }
        __syncthreads();
    }
    {
        _Float16* co = ctxb + ((size_t)b * T_ + t0) * E_;
#pragma unroll
        for (int nt = 0; nt < 8; ++nt)
#pragma unroll
            for (int r = 0; r < 4; ++r) {
                const int tl = wmB + fg * 4 + r;
                const int e = weB + nt * 16 + fr;
                co[(size_t)tl * E_ + e] = (_Float16)(acc2[nt][r] * rowinv_sh[tl]);
            }
    }
}

// K5: out[b,h,t] = (W2 . ctx^T + b_e2h + dec) * SCALE
__global__ __launch_bounds__(256) void k_out_mfma(const _Float16* __restrict__ W2,
                                                  const _Float16* __restrict__ ctxb,
                                                  const float* __restrict__ bias,
                                                  const float* __restrict__ dec,
                                                  float* __restrict__ out2) {
    MFMA_PROLOG
    const int b = blockIdx.z;
    const int h0 = blockIdx.y * 128;
    const int t0 = blockIdx.x * 128;
    const _Float16* Ab = W2 + (size_t)h0 * E_;
    const _Float16* Bb = ctxb + (size_t)b * T_ * E_ + (size_t)t0 * E_;
    for (int k0 = 0; k0 < E_; k0 += 32) {
        stage128x32_gl(Ab + k0, E_, Ash, wv, lane);
        stage128x32_gl(Bb + k0, E_, Bsh, wv, lane);
        __syncthreads();
        MFMA_BODY
        __syncthreads();
    }
    const int cr = (lane >> 4) * 4, cn = lane & 15;
    const float* decb = dec + (size_t)b * H_ * T_;
    float* ob = out2 + (size_t)b * H_ * T_;
#pragma unroll
    for (int mi = 0; mi < 4; ++mi)
#pragma unroll
        for (int r = 0; r < 4; ++r) {
            const int h = h0 + wm + mi * 16 + cr + r;
            const float bj = bias[h];
#pragma unroll
            for (int ni = 0; ni < 4; ++ni) {
                const int t = t0 + wn + ni * 16 + cn;
                const size_t idx = (size_t)h * T_ + t;
                ob[idx] = (acc[mi][ni][r] + bj + decb[idx]) * SCALE;
            }
        }
}

extern "C" void kernel_launch(void* const* d_in, const int* in_sizes, int n_in,
                              void* d_out, int out_size, void* d_ws, size_t ws_size,
                              hipStream_t stream) {
    const float* dec   = (const float*)d_in[0];  // [B,H,T]
    const float* emb   = (const float*)d_in[1];  // [B,T,E]
    const float* enc   = (const float*)d_in[2];  // [B,S,E] en_conved
    const float* encc  = (const float*)d_in[3];  // [B,S,E] en_combined
    const float* W_h2e = (const float*)d_in[4];  // [E,H]
    const float* b_h2e = (const float*)d_in[5];  // [E]
    const float* W_e2h = (const float*)d_in[6];  // [H,E]
    const float* b_e2h = (const float*)d_in[7];  // [H]

    float* a_out = (float*)d_out;                 // [B,T,S]
    float* out2  = a_out + (size_t)B_ * T_ * S_;  // [B,H,T]

    _Float16* ws    = (_Float16*)d_ws;
    _Float16* decT  = ws;                                  // [B,T,H] f16
    _Float16* encK  = decT + (size_t)B_ * T_ * H_;         // [B,S,E] f16
    _Float16* enccT = encK + (size_t)B_ * S_ * E_;         // [B,E,S] bf16 bits
    _Float16* W1b   = enccT + (size_t)B_ * S_ * E_;        // [E,H] f16
    _Float16* W2b   = W1b + (size_t)E_ * H_;               // [H,E] f16
    _Float16* Qb    = W2b + (size_t)H_ * E_;               // [B,T,E] f16
    _Float16* ctxb  = Qb + (size_t)B_ * T_ * E_;           // [B,T,E] f16

    const dim3 blk(256);
    const int NCAST = (B_ * S_ * E_ / 8) + (E_ * H_ / 8) + (H_ * E_ / 8);
    k_cast_all<<<dim3(NCAST / 256), blk, 0, stream>>>(enc, W_h2e, W_e2h, encK, W1b, W2b);
    k_tcast   <<<dim3(T_ / 32, H_ / 32, B_), blk, 0, stream>>>(dec, decT, H_, T_);   // [H,T]->[T,H] f16
    k_tcast_bf<<<dim3(E_ / 32, S_ / 32, B_), blk, 0, stream>>>(encc, (unsigned short*)enccT, S_, E_); // [S,E]->[E,S] bf16
    k_q_mfma  <<<dim3(E_ / 128, T_ / 64, B_),  blk, 0, stream>>>(decT, W1b, b_h2e, emb, Qb);
    k_mega    <<<dim3(T_ / 32, B_),            blk, 0, stream>>>(Qb, encK, enccT, a_out, ctxb);
    k_out_mfma<<<dim3(T_ / 128, H_ / 128, B_), blk, 0, stream>>>(W2b, ctxb, b_e2h, dec, out2);
}

// Round 6
// 388.936 us; speedup vs baseline: 1.1692x; 1.1692x over previous
//
#include <hip/hip_runtime.h>
#include <math.h>
#include <stdint.h>

#define B_ 8
#define H_ 512
#define E_ 256
#define T_ 2048
#define S_ 2048
static constexpr float SCALE = 0.83666002653407555f; // sqrt(0.7)
static constexpr float ESHIFT = 60.0f; // constant softmax shift: exact identity, f32-safe

typedef _Float16 half8 __attribute__((ext_vector_type(8)));
typedef _Float16 half4v __attribute__((ext_vector_type(4)));
typedef short short8 __attribute__((ext_vector_type(8)));
typedef unsigned short ushort8v __attribute__((ext_vector_type(8)));
typedef unsigned short ushort4v __attribute__((ext_vector_type(4)));
typedef float f32x4 __attribute__((ext_vector_type(4)));

__device__ __forceinline__ unsigned short f2bf(float f) { // RNE f32->bf16
    unsigned int u = __float_as_uint(f);
    u += 0x7FFFu + ((u >> 16) & 1u);
    return (unsigned short)(u >> 16);
}
__device__ __forceinline__ float bf2f(unsigned short u) {
    return __uint_as_float(((unsigned int)u) << 16);
}

// ---- fused fp32->fp16 casts for enc, W_h2e, W_e2h (one launch) ----
__global__ __launch_bounds__(256) void k_cast_all(const float* __restrict__ enc,
                                                  const float* __restrict__ w1,
                                                  const float* __restrict__ w2,
                                                  _Float16* __restrict__ encK,
                                                  _Float16* __restrict__ W1b,
                                                  _Float16* __restrict__ W2b) {
    const int i = blockIdx.x * 256 + threadIdx.x;
    const int N1 = B_ * S_ * E_ / 8;
    const int N2 = E_ * H_ / 8;
    const float* src; _Float16* dst; int off;
    if (i < N1)            { src = enc; dst = encK; off = i; }
    else if (i < N1 + N2)  { src = w1;  dst = W1b;  off = i - N1; }
    else                   { src = w2;  dst = W2b;  off = i - N1 - N2; }
    const float4* p = (const float4*)(src + (size_t)off * 8);
    const float4 a = p[0], b = p[1];
    half8 v;
    v[0] = (_Float16)a.x; v[1] = (_Float16)a.y; v[2] = (_Float16)a.z; v[3] = (_Float16)a.w;
    v[4] = (_Float16)b.x; v[5] = (_Float16)b.y; v[6] = (_Float16)b.z; v[7] = (_Float16)b.w;
    *(half8*)(dst + (size_t)off * 8) = v;
}

// ---- transpose + cast f16: in fp32 [Z,R,C] -> out fp16 [Z,C,R] ----
__global__ __launch_bounds__(256) void k_tcast(const float* __restrict__ in,
                                               _Float16* __restrict__ out, int R, int C) {
    __shared__ float tile[32][33];
    const size_t nb = (size_t)R * C;
    const float* inb = in + (size_t)blockIdx.z * nb;
    _Float16* outb = out + (size_t)blockIdx.z * nb;
    const int c0 = blockIdx.x * 32, r0 = blockIdx.y * 32;
    const int tr = threadIdx.x >> 3;
    const int tc = (threadIdx.x & 7) * 4;
    const float4 v = *(const float4*)(inb + (size_t)(r0 + tr) * C + c0 + tc);
    tile[tr][tc + 0] = v.x; tile[tr][tc + 1] = v.y;
    tile[tr][tc + 2] = v.z; tile[tr][tc + 3] = v.w;
    __syncthreads();
    half4v o;
    o[0] = (_Float16)tile[tc + 0][tr]; o[1] = (_Float16)tile[tc + 1][tr];
    o[2] = (_Float16)tile[tc + 2][tr]; o[3] = (_Float16)tile[tc + 3][tr];
    *(half4v*)(outb + (size_t)(c0 + tr) * R + r0 + tc) = o;
}

// ---- transpose + cast bf16: in fp32 [Z,R,C] -> out bf16 [Z,C,R] ----
__global__ __launch_bounds__(256) void k_tcast_bf(const float* __restrict__ in,
                                                  unsigned short* __restrict__ out, int R, int C) {
    __shared__ float tile[32][33];
    const size_t nb = (size_t)R * C;
    const float* inb = in + (size_t)blockIdx.z * nb;
    unsigned short* outb = out + (size_t)blockIdx.z * nb;
    const int c0 = blockIdx.x * 32, r0 = blockIdx.y * 32;
    const int tr = threadIdx.x >> 3;
    const int tc = (threadIdx.x & 7) * 4;
    const float4 v = *(const float4*)(inb + (size_t)(r0 + tr) * C + c0 + tc);
    tile[tr][tc + 0] = v.x; tile[tr][tc + 1] = v.y;
    tile[tr][tc + 2] = v.z; tile[tr][tc + 3] = v.w;
    __syncthreads();
    ushort4v o;
    o[0] = f2bf(tile[tc + 0][tr]); o[1] = f2bf(tile[tc + 1][tr]);
    o[2] = f2bf(tile[tc + 2][tr]); o[3] = f2bf(tile[tc + 3][tr]);
    *(ushort4v*)(outb + (size_t)(c0 + tr) * R + r0 + tc) = o;
}

// ---- async 16B global->LDS ----
__device__ __forceinline__ void gl_lds16(const _Float16* g, _Float16* l) {
    __builtin_amdgcn_global_load_lds(
        (const __attribute__((address_space(1))) void*)g,
        (__attribute__((address_space(3))) void*)l, 16, 0, 0);
}

// stage 64x32 2B-elem tile (rows k-contiguous, ld elems) -> linear [64][32] LDS (1 load/thread)
__device__ __forceinline__ void stage64x32_gl(const _Float16* __restrict__ g, int ld,
                                              _Float16* __restrict__ lds, int wv, int l) {
    const int r = (wv << 4) + (l >> 2);
    const int c = (l & 3) << 3;
    gl_lds16(g + (size_t)r * ld + c, lds + (wv << 9));
}

// stage 128x32 tile (2 loads/thread)
__device__ __forceinline__ void stage128x32_gl(const _Float16* __restrict__ g, int ld,
                                               _Float16* __restrict__ lds, int wv, int l) {
    const int r = (wv << 4) + (l >> 2);
    const int c = (l & 3) << 3;
    gl_lds16(g + (size_t)r * ld + c, lds + (wv << 9));
    gl_lds16(g + (size_t)(r + 64) * ld + c, lds + ((wv + 4) << 9));
}

// ---- 64x64 tile, double-buffered, 4 waves 2x2 (each 32x32, acc 2x2) ----
#define G64_PROLOG                                                      \
    __shared__ __align__(16) _Float16 Ash[2][64 * 32];                  \
    __shared__ __align__(16) _Float16 Bsh[2][64 * 32];                  \
    const int tid = threadIdx.x;                                        \
    const int lane = tid & 63, wv = tid >> 6;                           \
    const int wm = (wv >> 1) * 32, wn = (wv & 1) * 32;                  \
    const int fr = lane & 15, fk = (lane >> 4) * 8;                     \
    f32x4 acc[2][2] = {};

#define G64_STEP_F16(cur)                                               \
    {                                                                   \
        half8 af[2], bv[2];                                             \
        _Pragma("unroll")                                               \
        for (int i = 0; i < 2; ++i) {                                   \
            af[i] = *(const half8*)&Ash[cur][(wm + i * 16 + fr) * 32 + fk]; \
            bv[i] = *(const half8*)&Bsh[cur][(wn + i * 16 + fr) * 32 + fk]; \
        }                                                               \
        _Pragma("unroll")                                               \
        for (int mi = 0; mi < 2; ++mi)                                  \
            _Pragma("unroll")                                           \
            for (int ni = 0; ni < 2; ++ni)                              \
                acc[mi][ni] = __builtin_amdgcn_mfma_f32_16x16x32_f16(   \
                    af[mi], bv[ni], acc[mi][ni], 0, 0, 0);              \
    }

#define G64_STEP_BF16(cur)                                              \
    {                                                                   \
        short8 af[2], bv[2];                                            \
        _Pragma("unroll")                                               \
        for (int i = 0; i < 2; ++i) {                                   \
            af[i] = *(const short8*)&Ash[cur][(wm + i * 16 + fr) * 32 + fk]; \
            bv[i] = *(const short8*)&Bsh[cur][(wn + i * 16 + fr) * 32 + fk]; \
        }                                                               \
        _Pragma("unroll")                                               \
        for (int mi = 0; mi < 2; ++mi)                                  \
            _Pragma("unroll")                                           \
            for (int ni = 0; ni < 2; ++ni)                              \
                acc[mi][ni] = __builtin_amdgcn_mfma_f32_16x16x32_bf16(  \
                    af[mi], bv[ni], acc[mi][ni], 0, 0, 0);              \
    }

// K1: Q_f16[b,t,e] = f16((decT.W1^T + b_h2e + emb) * SCALE)  64x64 tiles, dbuf
__global__ __launch_bounds__(256) void k_q64(const _Float16* __restrict__ decT,
                                             const _Float16* __restrict__ W1,
                                             const float* __restrict__ bias,
                                             const float* __restrict__ emb,
                                             _Float16* __restrict__ Qb) {
    G64_PROLOG
    const int b = blockIdx.z, t0 = blockIdx.y * 64, e0 = blockIdx.x * 64;
    const _Float16* Ab = decT + ((size_t)b * T_ + t0) * H_;
    const _Float16* Bb = W1 + (size_t)e0 * H_;
    stage64x32_gl(Ab, H_, Ash[0], wv, lane);
    stage64x32_gl(Bb, H_, Bsh[0], wv, lane);
    __syncthreads();
    const int NK = H_ / 32;
    for (int k = 0; k < NK; ++k) {
        const int cur = k & 1;
        if (k + 1 < NK) {
            stage64x32_gl(Ab + (k + 1) * 32, H_, Ash[cur ^ 1], wv, lane);
            stage64x32_gl(Bb + (k + 1) * 32, H_, Bsh[cur ^ 1], wv, lane);
        }
        G64_STEP_F16(cur)
        __syncthreads();
    }
    const int cr = (lane >> 4) * 4, cn = lane & 15;
    const float* embb = emb + (size_t)b * T_ * E_;
    _Float16* Qo = Qb + (size_t)b * T_ * E_;
#pragma unroll
    for (int mi = 0; mi < 2; ++mi)
#pragma unroll
        for (int r = 0; r < 4; ++r) {
            const int t = t0 + wm + mi * 16 + cr + r;
#pragma unroll
            for (int ni = 0; ni < 2; ++ni) {
                const int e = e0 + wn + ni * 16 + cn;
                const float v = (acc[mi][ni][r] + bias[e] + embb[(size_t)t * E_ + e]) * SCALE;
                Qo[(size_t)t * E_ + e] = (_Float16)v;
            }
        }
}

// K2: energy -> P = exp(e-ESHIFT) bf16 + per-block partial row sums. 128x128 tile, dbuf.
__global__ __launch_bounds__(256) void k_pexp(const _Float16* __restrict__ Qb,
                                              const _Float16* __restrict__ Kb,
                                              unsigned short* __restrict__ P,
                                              float* __restrict__ gpart) {
    __shared__ __align__(16) _Float16 Ash[2][128 * 32];
    __shared__ __align__(16) _Float16 Bsh[2][128 * 32];
    __shared__ float psh[128][2];
    const int tid = threadIdx.x, lane = tid & 63, wv = tid >> 6;
    const int wm = (wv >> 1) * 64, wn = (wv & 1) * 64;
    const int fr = lane & 15, fk = (lane >> 4) * 8;
    f32x4 acc[4][4] = {};
    const int b = blockIdx.z, t0 = blockIdx.y * 128, s0 = blockIdx.x * 128;
    const _Float16* Ab = Qb + ((size_t)b * T_ + t0) * E_;
    const _Float16* Bb = Kb + ((size_t)b * S_ + s0) * E_;
    stage128x32_gl(Ab, E_, Ash[0], wv, lane);
    stage128x32_gl(Bb, E_, Bsh[0], wv, lane);
    __syncthreads();
    const int NK = E_ / 32;
    for (int k = 0; k < NK; ++k) {
        const int cur = k & 1;
        if (k + 1 < NK) {
            stage128x32_gl(Ab + (k + 1) * 32, E_, Ash[cur ^ 1], wv, lane);
            stage128x32_gl(Bb + (k + 1) * 32, E_, Bsh[cur ^ 1], wv, lane);
        }
        {
            half8 af[4], bv[4];
#pragma unroll
            for (int i = 0; i < 4; ++i) {
                af[i] = *(const half8*)&Ash[cur][(wm + i * 16 + fr) * 32 + fk];
                bv[i] = *(const half8*)&Bsh[cur][(wn + i * 16 + fr) * 32 + fk];
            }
#pragma unroll
            for (int mi = 0; mi < 4; ++mi)
#pragma unroll
                for (int ni = 0; ni < 4; ++ni)
                    acc[mi][ni] = __builtin_amdgcn_mfma_f32_16x16x32_f16(
                        af[mi], bv[ni], acc[mi][ni], 0, 0, 0);
        }
        __syncthreads();
    }
    const int cr = (lane >> 4) * 4, cn = lane & 15;
    unsigned short* Pb = P + ((size_t)b * T_ + t0) * S_ + s0;
#pragma unroll
    for (int mi = 0; mi < 4; ++mi)
#pragma unroll
        for (int r = 0; r < 4; ++r) {
            const int tl = wm + mi * 16 + cr + r;
            float rs = 0.f;
#pragma unroll
            for (int ni = 0; ni < 4; ++ni) {
                const float p = __expf(acc[mi][ni][r] - ESHIFT);
                rs += p;
                Pb[(size_t)tl * S_ + wn + ni * 16 + cn] = f2bf(p);
            }
            // reduce rs over the 16 cn lanes (masks stay within the 16-group)
#pragma unroll
            for (int m = 1; m < 16; m <<= 1) rs += __shfl_xor(rs, m);
            if (cn == 0) psh[tl][wv & 1] = rs;
        }
    __syncthreads();
    if (tid < 128)
        gpart[((size_t)b * T_ + t0 + tid) * 16 + blockIdx.x] = psh[tid][0] + psh[tid][1];
}

// K3: per row: sum partials -> rinv; a[row,:] = bf2f(P)*inv (pure streaming)
__global__ __launch_bounds__(256) void k_anorm(const unsigned short* __restrict__ P,
                                               const float* __restrict__ gpart,
                                               float* __restrict__ rinv,
                                               float* __restrict__ a) {
    const size_t row = blockIdx.x;
    __shared__ float sinv;
    const int tid = threadIdx.x;
    if (tid < 16) {
        float v = gpart[row * 16 + tid];
#pragma unroll
        for (int m = 1; m < 16; m <<= 1) v += __shfl_xor(v, m);
        if (tid == 0) {
            const float inv = 1.0f / v;
            sinv = inv;
            rinv[row] = inv;
        }
    }
    __syncthreads();
    const float inv = sinv;
    const unsigned short* p = P + row * (size_t)S_;
    float* o = a + row * (size_t)S_;
    const ushort8v v = *(const ushort8v*)(p + (size_t)tid * 8);
    float4 o0, o1;
    o0.x = bf2f(v[0]) * inv; o0.y = bf2f(v[1]) * inv;
    o0.z = bf2f(v[2]) * inv; o0.w = bf2f(v[3]) * inv;
    o1.x = bf2f(v[4]) * inv; o1.y = bf2f(v[5]) * inv;
    o1.z = bf2f(v[6]) * inv; o1.w = bf2f(v[7]) * inv;
    ((float4*)o)[tid * 2] = o0;
    ((float4*)o)[tid * 2 + 1] = o1;
}

// K4: ctx_f16 = (P . enccT) * rinv   bf16 MFMA, 64x64 tiles, dbuf, K=S
__global__ __launch_bounds__(256) void k_ctx64(const _Float16* __restrict__ Pa,
                                               const _Float16* __restrict__ Vt,
                                               const float* __restrict__ rinv,
                                               _Float16* __restrict__ ctxb) {
    G64_PROLOG
    const int b = blockIdx.z, t0 = blockIdx.y * 64, e0 = blockIdx.x * 64;
    const _Float16* Ab = Pa + ((size_t)b * T_ + t0) * S_;
    const _Float16* Bb = Vt + ((size_t)b * E_ + e0) * S_;
    stage64x32_gl(Ab, S_, Ash[0], wv, lane);
    stage64x32_gl(Bb, S_, Bsh[0], wv, lane);
    __syncthreads();
    const int NK = S_ / 32;
    for (int k = 0; k < NK; ++k) {
        const int cur = k & 1;
        if (k + 1 < NK) {
            stage64x32_gl(Ab + (k + 1) * 32, S_, Ash[cur ^ 1], wv, lane);
            stage64x32_gl(Bb + (k + 1) * 32, S_, Bsh[cur ^ 1], wv, lane);
        }
        G64_STEP_BF16(cur)
        __syncthreads();
    }
    const int cr = (lane >> 4) * 4, cn = lane & 15;
    _Float16* co = ctxb + (size_t)b * T_ * E_;
    const float* rib = rinv + (size_t)b * T_;
#pragma unroll
    for (int mi = 0; mi < 2; ++mi)
#pragma unroll
        for (int r = 0; r < 4; ++r) {
            const int t = t0 + wm + mi * 16 + cr + r;
            const float inv = rib[t];
#pragma unroll
            for (int ni = 0; ni < 2; ++ni) {
                const int e = e0 + wn + ni * 16 + cn;
                co[(size_t)t * E_ + e] = (_Float16)(acc[mi][ni][r] * inv);
            }
        }
}

// K5: out[b,h,t] = (W2 . ctx^T + b_e2h + dec) * SCALE   64x64 tiles, dbuf
__global__ __launch_bounds__(256) void k_out64(const _Float16* __restrict__ W2,
                                               const _Float16* __restrict__ ctxb,
                                               const float* __restrict__ bias,
                                               const float* __restrict__ dec,
                                               float* __restrict__ out2) {
    G64_PROLOG
    const int b = blockIdx.z, h0 = blockIdx.y * 64, t0 = blockIdx.x * 64;
    const _Float16* Ab = W2 + (size_t)h0 * E_;
    const _Float16* Bb = ctxb + ((size_t)b * T_ + t0) * E_;
    stage64x32_gl(Ab, E_, Ash[0], wv, lane);
    stage64x32_gl(Bb, E_, Bsh[0], wv, lane);
    __syncthreads();
    const int NK = E_ / 32;
    for (int k = 0; k < NK; ++k) {
        const int cur = k & 1;
        if (k + 1 < NK) {
            stage64x32_gl(Ab + (k + 1) * 32, E_, Ash[cur ^ 1], wv, lane);
            stage64x32_gl(Bb + (k + 1) * 32, E_, Bsh[cur ^ 1], wv, lane);
        }
        G64_STEP_F16(cur)
        __syncthreads();
    }
    const int cr = (lane >> 4) * 4, cn = lane & 15;
    const float* decb = dec + (size_t)b * H_ * T_;
    float* ob = out2 + (size_t)b * H_ * T_;
#pragma unroll
    for (int mi = 0; mi < 2; ++mi)
#pragma unroll
        for (int r = 0; r < 4; ++r) {
            const int h = h0 + wm + mi * 16 + cr + r;
            const float bj = bias[h];
#pragma unroll
            for (int ni = 0; ni < 2; ++ni) {
                const int t = t0 + wn + ni * 16 + cn;
                const size_t idx = (size_t)h * T_ + t;
                ob[idx] = (acc[mi][ni][r] + bj + decb[idx]) * SCALE;
            }
        }
}

extern "C" void kernel_launch(void* const* d_in, const int* in_sizes, int n_in,
                              void* d_out, int out_size, void* d_ws, size_t ws_size,
                              hipStream_t stream) {
    const float* dec   = (const float*)d_in[0];  // [B,H,T]
    const float* emb   = (const float*)d_in[1];  // [B,T,E]
    const float* enc   = (const float*)d_in[2];  // [B,S,E] en_conved
    const float* encc  = (const float*)d_in[3];  // [B,S,E] en_combined
    const float* W_h2e = (const float*)d_in[4];  // [E,H]
    const float* b_h2e = (const float*)d_in[5];  // [E]
    const float* W_e2h = (const float*)d_in[6];  // [H,E]
    const float* b_e2h = (const float*)d_in[7];  // [H]

    float* a_out = (float*)d_out;                 // [B,T,S]
    float* out2  = a_out + (size_t)B_ * T_ * S_;  // [B,H,T]

    _Float16* ws    = (_Float16*)d_ws;
    _Float16* decT  = ws;                                  // [B,T,H] f16
    _Float16* encK  = decT + (size_t)B_ * T_ * H_;         // [B,S,E] f16
    _Float16* enccT = encK + (size_t)B_ * S_ * E_;         // [B,E,S] bf16 bits
    _Float16* W1b   = enccT + (size_t)B_ * S_ * E_;        // [E,H] f16
    _Float16* W2b   = W1b + (size_t)E_ * H_;               // [H,E] f16
    _Float16* Qb    = W2b + (size_t)H_ * E_;               // [B,T,E] f16
    _Float16* ctxb  = Qb + (size_t)B_ * T_ * E_;           // [B,T,E] f16
    _Float16* Pbuf  = ctxb + (size_t)B_ * T_ * E_;         // [B,T,S] bf16 bits (~67MB)
    float*    gpart = (float*)(Pbuf + (size_t)B_ * T_ * S_); // [B*T][16] f32
    float*    rinv  = gpart + (size_t)B_ * T_ * 16;          // [B*T] f32

    const dim3 blk(256);
    const int NCAST = (B_ * S_ * E_ / 8) + (E_ * H_ / 8) + (H_ * E_ / 8);
    k_cast_all<<<dim3(NCAST / 256), blk, 0, stream>>>(enc, W_h2e, W_e2h, encK, W1b, W2b);
    k_tcast   <<<dim3(T_ / 32, H_ / 32, B_), blk, 0, stream>>>(dec, decT, H_, T_);   // [H,T]->[T,H]
    k_tcast_bf<<<dim3(E_ / 32, S_ / 32, B_), blk, 0, stream>>>(encc, (unsigned short*)enccT, S_, E_);
    k_q64  <<<dim3(E_ / 64, T_ / 64, B_),   blk, 0, stream>>>(decT, W1b, b_h2e, emb, Qb);
    k_pexp <<<dim3(S_ / 128, T_ / 128, B_), blk, 0, stream>>>(Qb, encK, (unsigned short*)Pbuf, gpart);
    k_anorm<<<dim3(B_ * T_),                blk, 0, stream>>>((const unsigned short*)Pbuf, gpart, rinv, a_out);
    k_ctx64<<<dim3(E_ / 64, T_ / 64, B_),   blk, 0, stream>>>(Pbuf, enccT, rinv, ctxb);
    k_out64<<<dim3(T_ / 64, H_ / 64, B_),   blk, 0, stream>>>(W2b, ctxb, b_e2h, dec, out2);
}

// Round 7
// 376.103 us; speedup vs baseline: 1.2091x; 1.0341x over previous
//
#include <hip/hip_runtime.h>
#include <math.h>
#include <stdint.h>

#define B_ 8
#define H_ 512
#define E_ 256
#define T_ 2048
#define S_ 2048
static constexpr float SCALE = 0.83666002653407555f; // sqrt(0.7)
static constexpr float ESHIFT = 60.0f; // constant softmax shift: exact identity, f32-safe

typedef _Float16 half8 __attribute__((ext_vector_type(8)));
typedef _Float16 half4v __attribute__((ext_vector_type(4)));
typedef short short8 __attribute__((ext_vector_type(8)));
typedef unsigned short ushort8v __attribute__((ext_vector_type(8)));
typedef unsigned short ushort4v __attribute__((ext_vector_type(4)));
typedef float f32x4 __attribute__((ext_vector_type(4)));

__device__ __forceinline__ unsigned short f2bf(float f) { // RNE f32->bf16
    unsigned int u = __float_as_uint(f);
    u += 0x7FFFu + ((u >> 16) & 1u);
    return (unsigned short)(u >> 16);
}
__device__ __forceinline__ float bf2f(unsigned short u) {
    return __uint_as_float(((unsigned int)u) << 16);
}

// XCD-aware remap: hardware block h -> work id wid so each XCD (h%8) owns a
// contiguous chunk of the work (one batch-slice) and its panels stay in its L2.
// Bijective since all grids are %8==0.
__device__ __forceinline__ void xcd_remap(int gx, int gy, int gz, int& x, int& y, int& z) {
    const int h = blockIdx.x + gx * (blockIdx.y + gy * blockIdx.z);
    const int nwg = gx * gy * gz;
    const int wid = (h & 7) * (nwg >> 3) + (h >> 3);
    x = wid % gx;
    y = (wid / gx) % gy;
    z = wid / (gx * gy);
}

// ---- fused fp32->fp16 casts for enc, W_h2e, W_e2h (one launch) ----
__global__ __launch_bounds__(256) void k_cast_all(const float* __restrict__ enc,
                                                  const float* __restrict__ w1,
                                                  const float* __restrict__ w2,
                                                  _Float16* __restrict__ encK,
                                                  _Float16* __restrict__ W1b,
                                                  _Float16* __restrict__ W2b) {
    const int i = blockIdx.x * 256 + threadIdx.x;
    const int N1 = B_ * S_ * E_ / 8;
    const int N2 = E_ * H_ / 8;
    const float* src; _Float16* dst; int off;
    if (i < N1)            { src = enc; dst = encK; off = i; }
    else if (i < N1 + N2)  { src = w1;  dst = W1b;  off = i - N1; }
    else                   { src = w2;  dst = W2b;  off = i - N1 - N2; }
    const float4* p = (const float4*)(src + (size_t)off * 8);
    const float4 a = p[0], b = p[1];
    half8 v;
    v[0] = (_Float16)a.x; v[1] = (_Float16)a.y; v[2] = (_Float16)a.z; v[3] = (_Float16)a.w;
    v[4] = (_Float16)b.x; v[5] = (_Float16)b.y; v[6] = (_Float16)b.z; v[7] = (_Float16)b.w;
    *(half8*)(dst + (size_t)off * 8) = v;
}

// ---- transpose + cast f16: in fp32 [Z,R,C] -> out fp16 [Z,C,R] ----
__global__ __launch_bounds__(256) void k_tcast(const float* __restrict__ in,
                                               _Float16* __restrict__ out, int R, int C) {
    __shared__ float tile[32][33];
    const size_t nb = (size_t)R * C;
    const float* inb = in + (size_t)blockIdx.z * nb;
    _Float16* outb = out + (size_t)blockIdx.z * nb;
    const int c0 = blockIdx.x * 32, r0 = blockIdx.y * 32;
    const int tr = threadIdx.x >> 3;
    const int tc = (threadIdx.x & 7) * 4;
    const float4 v = *(const float4*)(inb + (size_t)(r0 + tr) * C + c0 + tc);
    tile[tr][tc + 0] = v.x; tile[tr][tc + 1] = v.y;
    tile[tr][tc + 2] = v.z; tile[tr][tc + 3] = v.w;
    __syncthreads();
    half4v o;
    o[0] = (_Float16)tile[tc + 0][tr]; o[1] = (_Float16)tile[tc + 1][tr];
    o[2] = (_Float16)tile[tc + 2][tr]; o[3] = (_Float16)tile[tc + 3][tr];
    *(half4v*)(outb + (size_t)(c0 + tr) * R + r0 + tc) = o;
}

// ---- transpose + cast bf16: in fp32 [Z,R,C] -> out bf16 [Z,C,R] ----
__global__ __launch_bounds__(256) void k_tcast_bf(const float* __restrict__ in,
                                                  unsigned short* __restrict__ out, int R, int C) {
    __shared__ float tile[32][33];
    const size_t nb = (size_t)R * C;
    const float* inb = in + (size_t)blockIdx.z * nb;
    unsigned short* outb = out + (size_t)blockIdx.z * nb;
    const int c0 = blockIdx.x * 32, r0 = blockIdx.y * 32;
    const int tr = threadIdx.x >> 3;
    const int tc = (threadIdx.x & 7) * 4;
    const float4 v = *(const float4*)(inb + (size_t)(r0 + tr) * C + c0 + tc);
    tile[tr][tc + 0] = v.x; tile[tr][tc + 1] = v.y;
    tile[tr][tc + 2] = v.z; tile[tr][tc + 3] = v.w;
    __syncthreads();
    ushort4v o;
    o[0] = f2bf(tile[tc + 0][tr]); o[1] = f2bf(tile[tc + 1][tr]);
    o[2] = f2bf(tile[tc + 2][tr]); o[3] = f2bf(tile[tc + 3][tr]);
    *(ushort4v*)(outb + (size_t)(c0 + tr) * R + r0 + tc) = o;
}

// ---- async 16B global->LDS ----
__device__ __forceinline__ void gl_lds16(const _Float16* g, _Float16* l) {
    __builtin_amdgcn_global_load_lds(
        (const __attribute__((address_space(1))) void*)g,
        (__attribute__((address_space(3))) void*)l, 16, 0, 0);
}

// stage 64x32 2B-elem tile (rows k-contiguous, ld elems) -> linear [64][32] LDS (1 load/thread)
__device__ __forceinline__ void stage64x32_gl(const _Float16* __restrict__ g, int ld,
                                              _Float16* __restrict__ lds, int wv, int l) {
    const int r = (wv << 4) + (l >> 2);
    const int c = (l & 3) << 3;
    gl_lds16(g + (size_t)r * ld + c, lds + (wv << 9));
}

// stage 128x32 tile (2 loads/thread)
__device__ __forceinline__ void stage128x32_gl(const _Float16* __restrict__ g, int ld,
                                               _Float16* __restrict__ lds, int wv, int l) {
    const int r = (wv << 4) + (l >> 2);
    const int c = (l & 3) << 3;
    gl_lds16(g + (size_t)r * ld + c, lds + (wv << 9));
    gl_lds16(g + (size_t)(r + 64) * ld + c, lds + ((wv + 4) << 9));
}

// ---- 64x64 tile, double-buffered, 4 waves 2x2 (each 32x32, acc 2x2) ----
#define G64_PROLOG                                                      \
    __shared__ __align__(16) _Float16 Ash[2][64 * 32];                  \
    __shared__ __align__(16) _Float16 Bsh[2][64 * 32];                  \
    const int tid = threadIdx.x;                                        \
    const int lane = tid & 63, wv = tid >> 6;                           \
    const int wm = (wv >> 1) * 32, wn = (wv & 1) * 32;                  \
    const int fr = lane & 15, fk = (lane >> 4) * 8;                     \
    f32x4 acc[2][2] = {};

#define G64_STEP_F16(cur)                                               \
    {                                                                   \
        half8 af[2], bv[2];                                             \
        _Pragma("unroll")                                               \
        for (int i = 0; i < 2; ++i) {                                   \
            af[i] = *(const half8*)&Ash[cur][(wm + i * 16 + fr) * 32 + fk]; \
            bv[i] = *(const half8*)&Bsh[cur][(wn + i * 16 + fr) * 32 + fk]; \
        }                                                               \
        _Pragma("unroll")                                               \
        for (int mi = 0; mi < 2; ++mi)                                  \
            _Pragma("unroll")                                           \
            for (int ni = 0; ni < 2; ++ni)                              \
                acc[mi][ni] = __builtin_amdgcn_mfma_f32_16x16x32_f16(   \
                    af[mi], bv[ni], acc[mi][ni], 0, 0, 0);              \
    }

#define G64_STEP_BF16(cur)                                              \
    {                                                                   \
        short8 af[2], bv[2];                                            \
        _Pragma("unroll")                                               \
        for (int i = 0; i < 2; ++i) {                                   \
            af[i] = *(const short8*)&Ash[cur][(wm + i * 16 + fr) * 32 + fk]; \
            bv[i] = *(const short8*)&Bsh[cur][(wn + i * 16 + fr) * 32 + fk]; \
        }                                                               \
        _Pragma("unroll")                                               \
        for (int mi = 0; mi < 2; ++mi)                                  \
            _Pragma("unroll")                                           \
            for (int ni = 0; ni < 2; ++ni)                              \
                acc[mi][ni] = __builtin_amdgcn_mfma_f32_16x16x32_bf16(  \
                    af[mi], bv[ni], acc[mi][ni], 0, 0, 0);              \
    }

// K1: Q_f16[b,t,e] = f16((decT.W1^T + b_h2e + emb) * SCALE)  64x64 tiles, dbuf
__global__ __launch_bounds__(256) void k_q64(const _Float16* __restrict__ decT,
                                             const _Float16* __restrict__ W1,
                                             const float* __restrict__ bias,
                                             const float* __restrict__ emb,
                                             _Float16* __restrict__ Qb) {
    G64_PROLOG
    int bx, by, b;
    xcd_remap(E_ / 64, T_ / 64, B_, bx, by, b);
    const int t0 = by * 64, e0 = bx * 64;
    const _Float16* Ab = decT + ((size_t)b * T_ + t0) * H_;
    const _Float16* Bb = W1 + (size_t)e0 * H_;
    stage64x32_gl(Ab, H_, Ash[0], wv, lane);
    stage64x32_gl(Bb, H_, Bsh[0], wv, lane);
    __syncthreads();
    const int NK = H_ / 32;
    for (int k = 0; k < NK; ++k) {
        const int cur = k & 1;
        if (k + 1 < NK) {
            stage64x32_gl(Ab + (k + 1) * 32, H_, Ash[cur ^ 1], wv, lane);
            stage64x32_gl(Bb + (k + 1) * 32, H_, Bsh[cur ^ 1], wv, lane);
        }
        G64_STEP_F16(cur)
        __syncthreads();
    }
    const int cr = (lane >> 4) * 4, cn = lane & 15;
    const float* embb = emb + (size_t)b * T_ * E_;
    _Float16* Qo = Qb + (size_t)b * T_ * E_;
#pragma unroll
    for (int mi = 0; mi < 2; ++mi)
#pragma unroll
        for (int r = 0; r < 4; ++r) {
            const int t = t0 + wm + mi * 16 + cr + r;
#pragma unroll
            for (int ni = 0; ni < 2; ++ni) {
                const int e = e0 + wn + ni * 16 + cn;
                const float v = (acc[mi][ni][r] + bias[e] + embb[(size_t)t * E_ + e]) * SCALE;
                Qo[(size_t)t * E_ + e] = (_Float16)v;
            }
        }
}

// K2: energy -> P = exp(e-ESHIFT) bf16 + per-block partial row sums. 128x128 tile, dbuf.
__global__ __launch_bounds__(256) void k_pexp(const _Float16* __restrict__ Qb,
                                              const _Float16* __restrict__ Kb,
                                              unsigned short* __restrict__ P,
                                              float* __restrict__ gpart) {
    __shared__ __align__(16) _Float16 Ash[2][128 * 32];
    __shared__ __align__(16) _Float16 Bsh[2][128 * 32];
    __shared__ float psh[128][2];
    const int tid = threadIdx.x, lane = tid & 63, wv = tid >> 6;
    const int wm = (wv >> 1) * 64, wn = (wv & 1) * 64;
    const int fr = lane & 15, fk = (lane >> 4) * 8;
    f32x4 acc[4][4] = {};
    int bx, by, b;
    xcd_remap(S_ / 128, T_ / 128, B_, bx, by, b);
    const int t0 = by * 128, s0 = bx * 128;
    const _Float16* Ab = Qb + ((size_t)b * T_ + t0) * E_;
    const _Float16* Bb = Kb + ((size_t)b * S_ + s0) * E_;
    stage128x32_gl(Ab, E_, Ash[0], wv, lane);
    stage128x32_gl(Bb, E_, Bsh[0], wv, lane);
    __syncthreads();
    const int NK = E_ / 32;
    for (int k = 0; k < NK; ++k) {
        const int cur = k & 1;
        if (k + 1 < NK) {
            stage128x32_gl(Ab + (k + 1) * 32, E_, Ash[cur ^ 1], wv, lane);
            stage128x32_gl(Bb + (k + 1) * 32, E_, Bsh[cur ^ 1], wv, lane);
        }
        {
            half8 af[4], bv[4];
#pragma unroll
            for (int i = 0; i < 4; ++i) {
                af[i] = *(const half8*)&Ash[cur][(wm + i * 16 + fr) * 32 + fk];
                bv[i] = *(const half8*)&Bsh[cur][(wn + i * 16 + fr) * 32 + fk];
            }
#pragma unroll
            for (int mi = 0; mi < 4; ++mi)
#pragma unroll
                for (int ni = 0; ni < 4; ++ni)
                    acc[mi][ni] = __builtin_amdgcn_mfma_f32_16x16x32_f16(
                        af[mi], bv[ni], acc[mi][ni], 0, 0, 0);
        }
        __syncthreads();
    }
    const int cr = (lane >> 4) * 4, cn = lane & 15;
    unsigned short* Pb = P + ((size_t)b * T_ + t0) * S_ + s0;
#pragma unroll
    for (int mi = 0; mi < 4; ++mi)
#pragma unroll
        for (int r = 0; r < 4; ++r) {
            const int tl = wm + mi * 16 + cr + r;
            float rs = 0.f;
#pragma unroll
            for (int ni = 0; ni < 4; ++ni) {
                const float p = __expf(acc[mi][ni][r] - ESHIFT);
                rs += p;
                Pb[(size_t)tl * S_ + wn + ni * 16 + cn] = f2bf(p);
            }
#pragma unroll
            for (int m = 1; m < 16; m <<= 1) rs += __shfl_xor(rs, m);
            if (cn == 0) psh[tl][wv & 1] = rs;
        }
    __syncthreads();
    if (tid < 128)
        gpart[((size_t)b * T_ + t0 + tid) * 16 + bx] = psh[tid][0] + psh[tid][1];
}

// K3: per row: sum partials -> rinv; a[row,:] = bf2f(P)*inv (pure streaming)
__global__ __launch_bounds__(256) void k_anorm(const unsigned short* __restrict__ P,
                                               const float* __restrict__ gpart,
                                               float* __restrict__ rinv,
                                               float* __restrict__ a) {
    const size_t row = blockIdx.x;
    __shared__ float sinv;
    const int tid = threadIdx.x;
    if (tid < 16) {
        float v = gpart[row * 16 + tid];
#pragma unroll
        for (int m = 1; m < 16; m <<= 1) v += __shfl_xor(v, m);
        if (tid == 0) {
            const float inv = 1.0f / v;
            sinv = inv;
            rinv[row] = inv;
        }
    }
    __syncthreads();
    const float inv = sinv;
    const unsigned short* p = P + row * (size_t)S_;
    float* o = a + row * (size_t)S_;
    const ushort8v v = *(const ushort8v*)(p + (size_t)tid * 8);
    float4 o0, o1;
    o0.x = bf2f(v[0]) * inv; o0.y = bf2f(v[1]) * inv;
    o0.z = bf2f(v[2]) * inv; o0.w = bf2f(v[3]) * inv;
    o1.x = bf2f(v[4]) * inv; o1.y = bf2f(v[5]) * inv;
    o1.z = bf2f(v[6]) * inv; o1.w = bf2f(v[7]) * inv;
    ((float4*)o)[tid * 2] = o0;
    ((float4*)o)[tid * 2 + 1] = o1;
}

// K4: ctx_f16 = (P . enccT) * rinv   bf16 MFMA, 64x64 tiles, dbuf, K=S
__global__ __launch_bounds__(256) void k_ctx64(const _Float16* __restrict__ Pa,
                                               const _Float16* __restrict__ Vt,
                                               const float* __restrict__ rinv,
                                               _Float16* __restrict__ ctxb) {
    G64_PROLOG
    int bx, by, b;
    xcd_remap(E_ / 64, T_ / 64, B_, bx, by, b);
    const int t0 = by * 64, e0 = bx * 64;
    const _Float16* Ab = Pa + ((size_t)b * T_ + t0) * S_;
    const _Float16* Bb = Vt + ((size_t)b * E_ + e0) * S_;
    stage64x32_gl(Ab, S_, Ash[0], wv, lane);
    stage64x32_gl(Bb, S_, Bsh[0], wv, lane);
    __syncthreads();
    const int NK = S_ / 32;
    for (int k = 0; k < NK; ++k) {
        const int cur = k & 1;
        if (k + 1 < NK) {
            stage64x32_gl(Ab + (k + 1) * 32, S_, Ash[cur ^ 1], wv, lane);
            stage64x32_gl(Bb + (k + 1) * 32, S_, Bsh[cur ^ 1], wv, lane);
        }
        G64_STEP_BF16(cur)
        __syncthreads();
    }
    const int cr = (lane >> 4) * 4, cn = lane & 15;
    _Float16* co = ctxb + (size_t)b * T_ * E_;
    const float* rib = rinv + (size_t)b * T_;
#pragma unroll
    for (int mi = 0; mi < 2; ++mi)
#pragma unroll
        for (int r = 0; r < 4; ++r) {
            const int t = t0 + wm + mi * 16 + cr + r;
            const float inv = rib[t];
#pragma unroll
            for (int ni = 0; ni < 2; ++ni) {
                const int e = e0 + wn + ni * 16 + cn;
                co[(size_t)t * E_ + e] = (_Float16)(acc[mi][ni][r] * inv);
            }
        }
}

// K5: out[b,h,t] = (W2 . ctx^T + b_e2h + dec) * SCALE   64x64 tiles, dbuf
__global__ __launch_bounds__(256) void k_out64(const _Float16* __restrict__ W2,
                                               const _Float16* __restrict__ ctxb,
                                               const float* __restrict__ bias,
                                               const float* __restrict__ dec,
                                               float* __restrict__ out2) {
    G64_PROLOG
    int bx, by, b;
    xcd_remap(T_ / 64, H_ / 64, B_, bx, by, b);
    const int h0 = by * 64, t0 = bx * 64;
    const _Float16* Ab = W2 + (size_t)h0 * E_;
    const _Float16* Bb = ctxb + ((size_t)b * T_ + t0) * E_;
    stage64x32_gl(Ab, E_, Ash[0], wv, lane);
    stage64x32_gl(Bb, E_, Bsh[0], wv, lane);
    __syncthreads();
    const int NK = E_ / 32;
    for (int k = 0; k < NK; ++k) {
        const int cur = k & 1;
        if (k + 1 < NK) {
            stage64x32_gl(Ab + (k + 1) * 32, E_, Ash[cur ^ 1], wv, lane);
            stage64x32_gl(Bb + (k + 1) * 32, E_, Bsh[cur ^ 1], wv, lane);
        }
        G64_STEP_F16(cur)
        __syncthreads();
    }
    const int cr = (lane >> 4) * 4, cn = lane & 15;
    const float* decb = dec + (size_t)b * H_ * T_;
    float* ob = out2 + (size_t)b * H_ * T_;
#pragma unroll
    for (int mi = 0; mi < 2; ++mi)
#pragma unroll
        for (int r = 0; r < 4; ++r) {
            const int h = h0 + wm + mi * 16 + cr + r;
            const float bj = bias[h];
#pragma unroll
            for (int ni = 0; ni < 2; ++ni) {
                const int t = t0 + wn + ni * 16 + cn;
                const size_t idx = (size_t)h * T_ + t;
                ob[idx] = (acc[mi][ni][r] + bj + decb[idx]) * SCALE;
            }
        }
}

extern "C" void kernel_launch(void* const* d_in, const int* in_sizes, int n_in,
                              void* d_out, int out_size, void* d_ws, size_t ws_size,
                              hipStream_t stream) {
    const float* dec   = (const float*)d_in[0];  // [B,H,T]
    const float* emb   = (const float*)d_in[1];  // [B,T,E]
    const float* enc   = (const float*)d_in[2];  // [B,S,E] en_conved
    const float* encc  = (const float*)d_in[3];  // [B,S,E] en_combined
    const float* W_h2e = (const float*)d_in[4];  // [E,H]
    const float* b_h2e = (const float*)d_in[5];  // [E]
    const float* W_e2h = (const float*)d_in[6];  // [H,E]
    const float* b_e2h = (const float*)d_in[7];  // [H]

    float* a_out = (float*)d_out;                 // [B,T,S]
    float* out2  = a_out + (size_t)B_ * T_ * S_;  // [B,H,T]

    _Float16* ws    = (_Float16*)d_ws;
    _Float16* decT  = ws;                                  // [B,T,H] f16
    _Float16* encK  = decT + (size_t)B_ * T_ * H_;         // [B,S,E] f16
    _Float16* enccT = encK + (size_t)B_ * S_ * E_;         // [B,E,S] bf16 bits
    _Float16* W1b   = enccT + (size_t)B_ * S_ * E_;        // [E,H] f16
    _Float16* W2b   = W1b + (size_t)E_ * H_;               // [H,E] f16
    _Float16* Qb    = W2b + (size_t)H_ * E_;               // [B,T,E] f16
    _Float16* ctxb  = Qb + (size_t)B_ * T_ * E_;           // [B,T,E] f16
    _Float16* Pbuf  = ctxb + (size_t)B_ * T_ * E_;         // [B,T,S] bf16 bits (~67MB)
    float*    gpart = (float*)(Pbuf + (size_t)B_ * T_ * S_); // [B*T][16] f32
    float*    rinv  = gpart + (size_t)B_ * T_ * 16;          // [B*T] f32

    const dim3 blk(256);
    const int NCAST = (B_ * S_ * E_ / 8) + (E_ * H_ / 8) + (H_ * E_ / 8);
    k_cast_all<<<dim3(NCAST / 256), blk, 0, stream>>>(enc, W_h2e, W_e2h, encK, W1b, W2b);
    k_tcast   <<<dim3(T_ / 32, H_ / 32, B_), blk, 0, stream>>>(dec, decT, H_, T_);   // [H,T]->[T,H]
    k_tcast_bf<<<dim3(E_ / 32, S_ / 32, B_), blk, 0, stream>>>(encc, (unsigned short*)enccT, S_, E_);
    k_q64  <<<dim3(E_ / 64, T_ / 64, B_),   blk, 0, stream>>>(decT, W1b, b_h2e, emb, Qb);
    k_pexp <<<dim3(S_ / 128, T_ / 128, B_), blk, 0, stream>>>(Qb, encK, (unsigned short*)Pbuf, gpart);
    k_anorm<<<dim3(B_ * T_),                blk, 0, stream>>>((const unsigned short*)Pbuf, gpart, rinv, a_out);
    k_ctx64<<<dim3(E_ / 64, T_ / 64, B_),   blk, 0, stream>>>(Pbuf, enccT, rinv, ctxb);
    k_out64<<<dim3(T_ / 64, H_ / 64, B_),   blk, 0, stream>>>(W2b, ctxb, b_e2h, dec, out2);
}

// Round 9
// 367.743 us; speedup vs baseline: 1.2366x; 1.0227x over previous
//
#include <hip/hip_runtime.h>
#include <math.h>
#include <stdint.h>

#define B_ 8
#define H_ 512
#define E_ 256
#define T_ 2048
#define S_ 2048
static constexpr float SCALE = 0.83666002653407555f; // sqrt(0.7)
static constexpr float ESHIFT = 60.0f; // constant softmax shift: exact identity, f32-safe

typedef _Float16 half8 __attribute__((ext_vector_type(8)));
typedef _Float16 half4v __attribute__((ext_vector_type(4)));
typedef short short8 __attribute__((ext_vector_type(8)));
typedef unsigned short ushort8v __attribute__((ext_vector_type(8)));
typedef unsigned short ushort4v __attribute__((ext_vector_type(4)));
typedef float f32x4 __attribute__((ext_vector_type(4)));

__device__ __forceinline__ unsigned short f2bf(float f) { // RNE f32->bf16
    unsigned int u = __float_as_uint(f);
    u += 0x7FFFu + ((u >> 16) & 1u);
    return (unsigned short)(u >> 16);
}
__device__ __forceinline__ float bf2f(unsigned short u) {
    return __uint_as_float(((unsigned int)u) << 16);
}

// XCD-aware remap: each XCD (h%8) owns a contiguous chunk of work ids (one
// batch-slice); its operand panels stay in its private L2. Bijective (grids %8==0).
__device__ __forceinline__ void xcd_remap(int gx, int gy, int gz, int& x, int& y, int& z) {
    const int h = blockIdx.x + gx * (blockIdx.y + gy * blockIdx.z);
    const int nwg = gx * gy * gz;
    const int wid = (h & 7) * (nwg >> 3) + (h >> 3);
    x = wid % gx;
    y = (wid / gx) % gy;
    z = wid / (gx * gy);
}

// ---- fused prep: casts (enc,W1,W2) + transpose dec->decT f16 + encc->enccT bf16 ----
__global__ __launch_bounds__(256) void k_prep(const float* __restrict__ enc,
                                              const float* __restrict__ w1,
                                              const float* __restrict__ w2,
                                              const float* __restrict__ dec,
                                              const float* __restrict__ encc,
                                              _Float16* __restrict__ encK,
                                              _Float16* __restrict__ W1b,
                                              _Float16* __restrict__ W2b,
                                              _Float16* __restrict__ decT,
                                              unsigned short* __restrict__ enccT) {
    constexpr int NC = (B_ * S_ * E_ / 8 + E_ * H_ / 8 + H_ * E_ / 8) / 256; // 2176
    constexpr int NT1 = (T_ / 32) * (H_ / 32) * B_;                          // 8192
    __shared__ float tile[32][33];
    const int gb = blockIdx.x;
    const int tid = threadIdx.x;
    if (gb < NC) {
        const int i = gb * 256 + tid;
        const int N1 = B_ * S_ * E_ / 8;
        const int N2 = E_ * H_ / 8;
        const float* src; _Float16* dst; int off;
        if (i < N1)           { src = enc; dst = encK; off = i; }
        else if (i < N1 + N2) { src = w1;  dst = W1b;  off = i - N1; }
        else                  { src = w2;  dst = W2b;  off = i - N1 - N2; }
        const float4* p = (const float4*)(src + (size_t)off * 8);
        const float4 a = p[0], b = p[1];
        half8 v;
        v[0] = (_Float16)a.x; v[1] = (_Float16)a.y; v[2] = (_Float16)a.z; v[3] = (_Float16)a.w;
        v[4] = (_Float16)b.x; v[5] = (_Float16)b.y; v[6] = (_Float16)b.z; v[7] = (_Float16)b.w;
        *(half8*)(dst + (size_t)off * 8) = v;
        return;
    }
    const int tr = tid >> 3;
    const int tc = (tid & 7) * 4;
    if (gb < NC + NT1) {
        // dec [B,H,T] f32 -> decT [B,T,H] f16
        const int l = gb - NC;
        const int bx = l & 63, by = (l >> 6) & 15, bz = l >> 10;
        const int c0 = bx * 32, r0 = by * 32;
        const float* inb = dec + (size_t)bz * H_ * T_;
        _Float16* outb = decT + (size_t)bz * T_ * H_;
        const float4 v = *(const float4*)(inb + (size_t)(r0 + tr) * T_ + c0 + tc);
        tile[tr][tc + 0] = v.x; tile[tr][tc + 1] = v.y;
        tile[tr][tc + 2] = v.z; tile[tr][tc + 3] = v.w;
        __syncthreads();
        half4v o;
        o[0] = (_Float16)tile[tc + 0][tr]; o[1] = (_Float16)tile[tc + 1][tr];
        o[2] = (_Float16)tile[tc + 2][tr]; o[3] = (_Float16)tile[tc + 3][tr];
        *(half4v*)(outb + (size_t)(c0 + tr) * H_ + r0 + tc) = o;
        return;
    }
    {
        // encc [B,S,E] f32 -> enccT [B,E,S] bf16
        const int l = gb - NC - NT1;
        const int bx = l & 7, by = (l >> 3) & 63, bz = l >> 9;
        const int c0 = bx * 32, r0 = by * 32;
        const float* inb = encc + (size_t)bz * S_ * E_;
        unsigned short* outb = enccT + (size_t)bz * E_ * S_;
        const float4 v = *(const float4*)(inb + (size_t)(r0 + tr) * E_ + c0 + tc);
        tile[tr][tc + 0] = v.x; tile[tr][tc + 1] = v.y;
        tile[tr][tc + 2] = v.z; tile[tr][tc + 3] = v.w;
        __syncthreads();
        ushort4v o;
        o[0] = f2bf(tile[tc + 0][tr]); o[1] = f2bf(tile[tc + 1][tr]);
        o[2] = f2bf(tile[tc + 2][tr]); o[3] = f2bf(tile[tc + 3][tr]);
        *(ushort4v*)(outb + (size_t)(c0 + tr) * S_ + r0 + tc) = o;
    }
}

// ---- async 16B global->LDS ----
__device__ __forceinline__ void gl_lds16(const _Float16* g, _Float16* l) {
    __builtin_amdgcn_global_load_lds(
        (const __attribute__((address_space(1))) void*)g,
        (__attribute__((address_space(3))) void*)l, 16, 0, 0);
}

// stage 64x32 2B-elem tile (rows k-contiguous, ld elems) -> linear [64][32] LDS
__device__ __forceinline__ void stage64x32_gl(const _Float16* __restrict__ g, int ld,
                                              _Float16* __restrict__ lds, int wv, int l) {
    const int r = (wv << 4) + (l >> 2);
    const int c = (l & 3) << 3;
    gl_lds16(g + (size_t)r * ld + c, lds + (wv << 9));
}

// stage 128x32 tile (2 loads/thread)
__device__ __forceinline__ void stage128x32_gl(const _Float16* __restrict__ g, int ld,
                                               _Float16* __restrict__ lds, int wv, int l) {
    const int r = (wv << 4) + (l >> 2);
    const int c = (l & 3) << 3;
    gl_lds16(g + (size_t)r * ld + c, lds + (wv << 9));
    gl_lds16(g + (size_t)(r + 64) * ld + c, lds + ((wv + 4) << 9));
}

// ---- 64x64 tile, double-buffered, 4 waves 2x2 (each 32x32, acc 2x2) ----
#define G64_PROLOG                                                      \
    __shared__ __align__(16) _Float16 Ash[2][64 * 32];                  \
    __shared__ __align__(16) _Float16 Bsh[2][64 * 32];                  \
    const int tid = threadIdx.x;                                        \
    const int lane = tid & 63, wv = tid >> 6;                           \
    const int wm = (wv >> 1) * 32, wn = (wv & 1) * 32;                  \
    const int fr = lane & 15, fk = (lane >> 4) * 8;                     \
    f32x4 acc[2][2] = {};

#define G64_STEP_F16(cur)                                               \
    {                                                                   \
        half8 af[2], bv[2];                                             \
        _Pragma("unroll")                                               \
        for (int i = 0; i < 2; ++i) {                                   \
            af[i] = *(const half8*)&Ash[cur][(wm + i * 16 + fr) * 32 + fk]; \
            bv[i] = *(const half8*)&Bsh[cur][(wn + i * 16 + fr) * 32 + fk]; \
        }                                                               \
        _Pragma("unroll")                                               \
        for (int mi = 0; mi < 2; ++mi)                                  \
            _Pragma("unroll")                                           \
            for (int ni = 0; ni < 2; ++ni)                              \
                acc[mi][ni] = __builtin_amdgcn_mfma_f32_16x16x32_f16(   \
                    af[mi], bv[ni], acc[mi][ni], 0, 0, 0);              \
    }

#define G64_STEP_BF16(cur)                                              \
    {                                                                   \
        short8 af[2], bv[2];                                            \
        _Pragma("unroll")                                               \
        for (int i = 0; i < 2; ++i) {                                   \
            af[i] = *(const short8*)&Ash[cur][(wm + i * 16 + fr) * 32 + fk]; \
            bv[i] = *(const short8*)&Bsh[cur][(wn + i * 16 + fr) * 32 + fk]; \
        }                                                               \
        _Pragma("unroll")                                               \
        for (int mi = 0; mi < 2; ++mi)                                  \
            _Pragma("unroll")                                           \
            for (int ni = 0; ni < 2; ++ni)                              \
                acc[mi][ni] = __builtin_amdgcn_mfma_f32_16x16x32_bf16(  \
                    af[mi], bv[ni], acc[mi][ni], 0, 0, 0);              \
    }

// K1: Q_f16[b,t,e] = f16((decT.W1^T + b_h2e + emb) * SCALE)  64x64 tiles, dbuf
__global__ __launch_bounds__(256) void k_q64(const _Float16* __restrict__ decT,
                                             const _Float16* __restrict__ W1,
                                             const float* __restrict__ bias,
                                             const float* __restrict__ emb,
                                             _Float16* __restrict__ Qb) {
    G64_PROLOG
    int bx, by, b;
    xcd_remap(E_ / 64, T_ / 64, B_, bx, by, b);
    const int t0 = by * 64, e0 = bx * 64;
    const _Float16* Ab = decT + ((size_t)b * T_ + t0) * H_;
    const _Float16* Bb = W1 + (size_t)e0 * H_;
    stage64x32_gl(Ab, H_, Ash[0], wv, lane);
    stage64x32_gl(Bb, H_, Bsh[0], wv, lane);
    __syncthreads();
    const int NK = H_ / 32;
    for (int k = 0; k < NK; ++k) {
        const int cur = k & 1;
        if (k + 1 < NK) {
            stage64x32_gl(Ab + (k + 1) * 32, H_, Ash[cur ^ 1], wv, lane);
            stage64x32_gl(Bb + (k + 1) * 32, H_, Bsh[cur ^ 1], wv, lane);
        }
        G64_STEP_F16(cur)
        __syncthreads();
    }
    const int cr = (lane >> 4) * 4, cn = lane & 15;
    const float* embb = emb + (size_t)b * T_ * E_;
    _Float16* Qo = Qb + (size_t)b * T_ * E_;
#pragma unroll
    for (int mi = 0; mi < 2; ++mi)
#pragma unroll
        for (int r = 0; r < 4; ++r) {
            const int t = t0 + wm + mi * 16 + cr + r;
#pragma unroll
            for (int ni = 0; ni < 2; ++ni) {
                const int e = e0 + wn + ni * 16 + cn;
                const float v = (acc[mi][ni][r] + bias[e] + embb[(size_t)t * E_ + e]) * SCALE;
                Qo[(size_t)t * E_ + e] = (_Float16)v;
            }
        }
}

// K2: energy -> P = exp(e-ESHIFT) bf16 + per-block partial row sums. 128x128 tile, dbuf.
__global__ __launch_bounds__(256) void k_pexp(const _Float16* __restrict__ Qb,
                                              const _Float16* __restrict__ Kb,
                                              unsigned short* __restrict__ P,
                                              float* __restrict__ gpart) {
    __shared__ __align__(16) _Float16 Ash[2][128 * 32];
    __shared__ __align__(16) _Float16 Bsh[2][128 * 32];
    __shared__ float psh[128][2];
    const int tid = threadIdx.x, lane = tid & 63, wv = tid >> 6;
    const int wm = (wv >> 1) * 64, wn = (wv & 1) * 64;
    const int fr = lane & 15, fk = (lane >> 4) * 8;
    f32x4 acc[4][4] = {};
    int bx, by, b;
    xcd_remap(S_ / 128, T_ / 128, B_, bx, by, b);
    const int t0 = by * 128, s0 = bx * 128;
    const _Float16* Ab = Qb + ((size_t)b * T_ + t0) * E_;
    const _Float16* Bb = Kb + ((size_t)b * S_ + s0) * E_;
    stage128x32_gl(Ab, E_, Ash[0], wv, lane);
    stage128x32_gl(Bb, E_, Bsh[0], wv, lane);
    __syncthreads();
    const int NK = E_ / 32;
    for (int k = 0; k < NK; ++k) {
        const int cur = k & 1;
        if (k + 1 < NK) {
            stage128x32_gl(Ab + (k + 1) * 32, E_, Ash[cur ^ 1], wv, lane);
            stage128x32_gl(Bb + (k + 1) * 32, E_, Bsh[cur ^ 1], wv, lane);
        }
        {
            half8 af[4], bv[4];
#pragma unroll
            for (int i = 0; i < 4; ++i) {
                af[i] = *(const half8*)&Ash[cur][(wm + i * 16 + fr) * 32 + fk];
                bv[i] = *(const half8*)&Bsh[cur][(wn + i * 16 + fr) * 32 + fk];
            }
#pragma unroll
            for (int mi = 0; mi < 4; ++mi)
#pragma unroll
                for (int ni = 0; ni < 4; ++ni)
                    acc[mi][ni] = __builtin_amdgcn_mfma_f32_16x16x32_f16(
                        af[mi], bv[ni], acc[mi][ni], 0, 0, 0);
        }
        __syncthreads();
    }
    const int cr = (lane >> 4) * 4, cn = lane & 15;
    unsigned short* Pb = P + ((size_t)b * T_ + t0) * S_ + s0;
#pragma unroll
    for (int mi = 0; mi < 4; ++mi)
#pragma unroll
        for (int r = 0; r < 4; ++r) {
            const int tl = wm + mi * 16 + cr + r;
            float rs = 0.f;
#pragma unroll
            for (int ni = 0; ni < 4; ++ni) {
                const float p = __expf(acc[mi][ni][r] - ESHIFT);
                rs += p;
                Pb[(size_t)tl * S_ + wn + ni * 16 + cn] = f2bf(p);
            }
#pragma unroll
            for (int m = 1; m < 16; m <<= 1) rs += __shfl_xor(rs, m);
            if (cn == 0) psh[tl][wv & 1] = rs;
        }
    __syncthreads();
    if (tid < 128)
        gpart[((size_t)b * T_ + t0 + tid) * 16 + bx] = psh[tid][0] + psh[tid][1];
}

// K4: ctx = (P.V)*rinv, with FUSED a-write: the staged P chunk matching this
// block's column quarter is normalized and written to a_out (replaces k_anorm).
// rinv computed in prologue from gpart.
__global__ __launch_bounds__(256) void k_ctx64(const _Float16* __restrict__ Pa,
                                               const _Float16* __restrict__ Vt,
                                               const float* __restrict__ gpart,
                                               float* __restrict__ a_out,
                                               _Float16* __restrict__ ctxb) {
    G64_PROLOG
    __shared__ float rinv_sh[64];
    int bx, by, b;
    xcd_remap(E_ / 64, T_ / 64, B_, bx, by, b);
    const int t0 = by * 64, e0 = bx * 64;
    const _Float16* Ab = Pa + ((size_t)b * T_ + t0) * S_;
    const _Float16* Bb = Vt + ((size_t)b * E_ + e0) * S_;
    stage64x32_gl(Ab, S_, Ash[0], wv, lane);
    stage64x32_gl(Bb, S_, Bsh[0], wv, lane);
    if (tid < 64) {
        const float* gp = gpart + ((size_t)b * T_ + t0 + tid) * 16;
        float s = 0.f;
#pragma unroll
        for (int i = 0; i < 16; ++i) s += gp[i];
        rinv_sh[tid] = 1.0f / s;
    }
    __syncthreads();
    const int ar = tid >> 2, ac = (tid & 3) * 8;
    const float ainv = rinv_sh[ar];
    float* arow = a_out + ((size_t)b * T_ + t0 + ar) * S_ + ac;
    const int NK = S_ / 32;
    for (int k = 0; k < NK; ++k) {
        const int cur = k & 1;
        if (k + 1 < NK) {
            stage64x32_gl(Ab + (k + 1) * 32, S_, Ash[cur ^ 1], wv, lane);
            stage64x32_gl(Bb + (k + 1) * 32, S_, Bsh[cur ^ 1], wv, lane);
        }
        G64_STEP_BF16(cur)
        if ((k >> 4) == bx) {
            // write a for the staged chunk: a[t0+ar][k*32+ac .. +8]
            const ushort8v pv = *(const ushort8v*)&Ash[cur][ar * 32 + ac];
            float4 w0, w1;
            w0.x = bf2f(pv[0]) * ainv; w0.y = bf2f(pv[1]) * ainv;
            w0.z = bf2f(pv[2]) * ainv; w0.w = bf2f(pv[3]) * ainv;
            w1.x = bf2f(pv[4]) * ainv; w1.y = bf2f(pv[5]) * ainv;
            w1.z = bf2f(pv[6]) * ainv; w1.w = bf2f(pv[7]) * ainv;
            ((float4*)(arow + k * 32))[0] = w0;
            ((float4*)(arow + k * 32))[1] = w1;
        }
        __syncthreads();
    }
    const int cr = (lane >> 4) * 4, cn = lane & 15;
    _Float16* co = ctxb + (size_t)b * T_ * E_;
#pragma unroll
    for (int mi = 0; mi < 2; ++mi)
#pragma unroll
        for (int r = 0; r < 4; ++r) {
            const int tl = wm + mi * 16 + cr + r;
            const float inv = rinv_sh[tl];
#pragma unroll
            for (int ni = 0; ni < 2; ++ni) {
                const int e = e0 + wn + ni * 16 + cn;
                co[(size_t)(t0 + tl) * E_ + e] = (_Float16)(acc[mi][ni][r] * inv);
            }
        }
}

// K5: out[b,h,t] = (W2 . ctx^T + b_e2h + dec) * SCALE   64x64 tiles, dbuf
__global__ __launch_bounds__(256) void k_out64(const _Float16* __restrict__ W2,
                                               const _Float16* __restrict__ ctxb,
                                               const float* __restrict__ bias,
                                               const float* __restrict__ dec,
                                               float* __restrict__ out2) {
    G64_PROLOG
    int bx, by, b;
    xcd_remap(T_ / 64, H_ / 64, B_, bx, by, b);
    const int h0 = by * 64, t0 = bx * 64;
    const _Float16* Ab = W2 + (size_t)h0 * E_;
    const _Float16* Bb = ctxb + ((size_t)b * T_ + t0) * E_;
    stage64x32_gl(Ab, E_, Ash[0], wv, lane);
    stage64x32_gl(Bb, E_, Bsh[0], wv, lane);
    __syncthreads();
    const int NK = E_ / 32;
    for (int k = 0; k < NK; ++k) {
        const int cur = k & 1;
        if (k + 1 < NK) {
            stage64x32_gl(Ab + (k + 1) * 32, E_, Ash[cur ^ 1], wv, lane);
            stage64x32_gl(Bb + (k + 1) * 32, E_, Bsh[cur ^ 1], wv, lane);
        }
        G64_STEP_F16(cur)
        __syncthreads();
    }
    const int cr = (lane >> 4) * 4, cn = lane & 15;
    const float* decb = dec + (size_t)b * H_ * T_;
    float* ob = out2 + (size_t)b * H_ * T_;
#pragma unroll
    for (int mi = 0; mi < 2; ++mi)
#pragma unroll
        for (int r = 0; r < 4; ++r) {
            const int h = h0 + wm + mi * 16 + cr + r;
            const float bj = bias[h];
#pragma unroll
            for (int ni = 0; ni < 2; ++ni) {
                const int t = t0 + wn + ni * 16 + cn;
                const size_t idx = (size_t)h * T_ + t;
                ob[idx] = (acc[mi][ni][r] + bj + decb[idx]) * SCALE;
            }
        }
}

extern "C" void kernel_launch(void* const* d_in, const int* in_sizes, int n_in,
                              void* d_out, int out_size, void* d_ws, size_t ws_size,
                              hipStream_t stream) {
    const float* dec   = (const float*)d_in[0];  // [B,H,T]
    const float* emb   = (const float*)d_in[1];  // [B,T,E]
    const float* enc   = (const float*)d_in[2];  // [B,S,E] en_conved
    const float* encc  = (const float*)d_in[3];  // [B,S,E] en_combined
    const float* W_h2e = (const float*)d_in[4];  // [E,H]
    const float* b_h2e = (const float*)d_in[5];  // [E]
    const float* W_e2h = (const float*)d_in[6];  // [H,E]
    const float* b_e2h = (const float*)d_in[7];  // [H]

    float* a_out = (float*)d_out;                 // [B,T,S]
    float* out2  = a_out + (size_t)B_ * T_ * S_;  // [B,H,T]

    _Float16* ws    = (_Float16*)d_ws;
    _Float16* decT  = ws;                                  // [B,T,H] f16
    _Float16* encK  = decT + (size_t)B_ * T_ * H_;         // [B,S,E] f16
    _Float16* enccT = encK + (size_t)B_ * S_ * E_;         // [B,E,S] bf16 bits
    _Float16* W1b   = enccT + (size_t)B_ * S_ * E_;        // [E,H] f16
    _Float16* W2b   = W1b + (size_t)E_ * H_;               // [H,E] f16
    _Float16* Qb    = W2b + (size_t)H_ * E_;               // [B,T,E] f16
    _Float16* ctxb  = Qb + (size_t)B_ * T_ * E_;           // [B,T,E] f16
    _Float16* Pbuf  = ctxb + (size_t)B_ * T_ * E_;         // [B,T,S] bf16 bits (~67MB)
    float*    gpart = (float*)(Pbuf + (size_t)B_ * T_ * S_); // [B*T][16] f32

    const dim3 blk(256);
    constexpr int NPREP = (B_ * S_ * E_ / 8 + E_ * H_ / 8 + H_ * E_ / 8) / 256
                        + (T_ / 32) * (H_ / 32) * B_
                        + (E_ / 32) * (S_ / 32) * B_;      // 14464
    k_prep <<<dim3(NPREP),                 blk, 0, stream>>>(enc, W_h2e, W_e2h, dec, encc,
                                                             encK, W1b, W2b, decT,
                                                             (unsigned short*)enccT);
    k_q64  <<<dim3(E_ / 64, T_ / 64, B_),   blk, 0, stream>>>(decT, W1b, b_h2e, emb, Qb);
    k_pexp <<<dim3(S_ / 128, T_ / 128, B_), blk, 0, stream>>>(Qb, encK, (unsigned short*)Pbuf, gpart);
    k_ctx64<<<dim3(E_ / 64, T_ / 64, B_),   blk, 0, stream>>>(Pbuf, enccT, gpart, a_out, ctxb);
    k_out64<<<dim3(T_ / 64, H_ / 64, B_),   blk, 0, stream>>>(W2b, ctxb, b_e2h, dec, out2);
}